// Round 8
// baseline (61.521 us; speedup 1.0000x reference)
//
#include <hip/hip_runtime.h>
#include <hip/hip_bf16.h>
#include <cstdint>

#define SEQ   2048
#define HD    64
#define NBH   32
#define QBLK  64
#define KVBLK 64
#define NQT   (SEQ / QBLK)  // 32
#define LDK   72            // padded LDS stride (shorts): 144B rows
// scale = 1/sqrt(64) * log2(e)  (softmax in exp2 domain)
#define QSC   0.18033688011112042f
#define THR   11.0f         // defer-max threshold (log2 domain)

typedef __attribute__((ext_vector_type(8))) short short8;
typedef __attribute__((ext_vector_type(4))) float floatx4;
typedef __attribute__((ext_vector_type(2))) unsigned uint2v;

#if __has_builtin(__builtin_amdgcn_exp2f)
#define EXP2(x) __builtin_amdgcn_exp2f(x)
#else
#define EXP2(x) __expf((x) * 0.69314718055994531f)
#endif

static __device__ __forceinline__ short f2bf(float f) {
    union { float f; unsigned u; } x; x.f = f;
    return (short)((x.u + 0x7fffu + ((x.u >> 16) & 1u)) >> 16);  // RNE
}
static __device__ __forceinline__ unsigned pkbf(float a, float b) {
    __hip_bfloat162 h = __float22bfloat162_rn(make_float2(a, b));
    union { __hip_bfloat162 h; unsigned u; } c; c.h = h; return c.u;
}

// ---------------- prep kernels (proven) ----------------

__global__ __launch_bounds__(256)
void conv_k_kernel(const float* __restrict__ K, short* __restrict__ Kb) {
    size_t i = ((size_t)blockIdx.x * 256 + threadIdx.x) * 8;
    float4 a = *(const float4*)(K + i);
    float4 b = *(const float4*)(K + i + 4);
    union { unsigned u[4]; short8 s; } cv;
    cv.u[0] = pkbf(a.x, a.y); cv.u[1] = pkbf(a.z, a.w);
    cv.u[2] = pkbf(b.x, b.y); cv.u[3] = pkbf(b.z, b.w);
    *(short8*)(Kb + i) = cv.s;
}

__global__ __launch_bounds__(256)
void trans_v_kernel(const float* __restrict__ V, short* __restrict__ Vt) {
    __shared__ __align__(16) short Vs[64][72];
    const int tid = threadIdx.x;
    const int bh = blockIdx.x >> 5;
    const int t  = blockIdx.x & 31;
    const float* src = V + ((size_t)bh * SEQ + (size_t)t * 64) * HD;
    #pragma unroll
    for (int i = 0; i < 4; ++i) {
        int idx = i * 256 + tid;
        int r = idx >> 4; int c = (idx & 15) * 4;
        float4 f = *(const float4*)(src + r * HD + c);
        Vs[c + 0][r] = f2bf(f.x); Vs[c + 1][r] = f2bf(f.y);
        Vs[c + 2][r] = f2bf(f.z); Vs[c + 3][r] = f2bf(f.w);
    }
    __syncthreads();
    short* dst = Vt + (size_t)bh * HD * SEQ + t * 64;
    #pragma unroll
    for (int i = 0; i < 2; ++i) {
        int idx = i * 256 + tid;
        int d = idx >> 3; int j = idx & 7;
        short8 v = *(const short8*)&Vs[d][j * 8];
        *(short8*)(dst + (size_t)d * SEQ + j * 8) = v;
    }
}

// ---------------- main attention kernel (v8) ----------------
// v7b body (swapped QK^T, lane-local softmax, packed P writes, defer-max,
// dbuf K/V with ONE barrier per tile, reg-prefetch) + PAIRED Q-TILES:
// each block processes q-tile qiA=31-p then qiB=p as one flat 33-tile loop
// -> 512 blocks of IDENTICAL work (no imbalance, no tail), phase B's KV is
// L2-hot from phase A. Buffer parity continues across the phase boundary
// (publish of tile g only needs readers of tile g-2 done -> sync at g-1).

#define FINAL_STORE(qb)                                                        \
    do {                                                                       \
        float lt = l_s;                                                        \
        lt += __shfl_xor(lt, 16);                                              \
        lt += __shfl_xor(lt, 32);                                              \
        const float linv = 1.0f / lt;                                          \
        _Pragma("unroll")                                                      \
        for (int e = 0; e < 4; ++e) {                                          \
            const float li = __shfl(linv, lg4 + e);                            \
            const int row = (qb) + wv * 16 + lg4 + e;                          \
            _Pragma("unroll")                                                  \
            for (int dt = 0; dt < 4; ++dt)                                     \
                Op[(size_t)row * HD + dt * 16 + l15] = o_acc[dt][e] * li;      \
        }                                                                      \
    } while (0)

__global__ __launch_bounds__(256, 4)
void fa_fwd_v8(const float* __restrict__ Q, const short* __restrict__ Kg,
               const short* __restrict__ Vtg, float* __restrict__ O)
{
    const int tid  = threadIdx.x;
    const int lane = tid & 63;
    const int wv   = tid >> 6;
    const int l15  = lane & 15;
    const int lg   = lane >> 4;
    const int lg4  = lg * 4;
    const int dofs = lg * 8;

    const int bh  = blockIdx.x & (NBH - 1);
    const int pr  = blockIdx.x >> 5;        // 0..15
    const int qiA = (NQT - 1) - pr;         // 16..31 (heavy phase)
    const int qiB = pr;                     // 0..15  (light phase)
    const int TT  = NQT + 1;                // (qiA+1)+(qiB+1) = 33 tiles

    const float* Qp = Q   + (size_t)bh * SEQ * HD;
    const short* Kp = Kg  + (size_t)bh * SEQ * HD;
    const short* Vp = Vtg + (size_t)bh * HD * SEQ;
    float*       Op = O   + (size_t)bh * SEQ * HD;

    __shared__ __align__(16) short K_lds[2][KVBLK][LDK];
    __shared__ __align__(16) short Vt_lds[2][HD][LDK];
    __shared__ __align__(16) short Pl[4][16][LDK];

    const int r0 = tid >> 3,         j0 = tid & 7;
    const int r1 = (tid + 256) >> 3, j1 = tid & 7;
    const int kg0 = r0 * HD + j0 * 8, kg1 = r1 * HD + j1 * 8;
    const int vg0 = r0 * SEQ + j0 * 8, vg1 = r1 * SEQ + j1 * 8;

    // ---- Q fragments for BOTH phases (B-operand), scale folded ----
    short8 qfA0, qfA1, qfB0, qfB1;
    {
        union { unsigned u[4]; short8 s; } cv;
        const float* srcA = Qp + (size_t)(qiA * QBLK + wv * 16 + l15) * HD + dofs;
        float4 f0 = *(const float4*)(srcA);
        float4 f1 = *(const float4*)(srcA + 4);
        cv.u[0] = pkbf(f0.x * QSC, f0.y * QSC); cv.u[1] = pkbf(f0.z * QSC, f0.w * QSC);
        cv.u[2] = pkbf(f1.x * QSC, f1.y * QSC); cv.u[3] = pkbf(f1.z * QSC, f1.w * QSC);
        qfA0 = cv.s;
        f0 = *(const float4*)(srcA + 32);
        f1 = *(const float4*)(srcA + 36);
        cv.u[0] = pkbf(f0.x * QSC, f0.y * QSC); cv.u[1] = pkbf(f0.z * QSC, f0.w * QSC);
        cv.u[2] = pkbf(f1.x * QSC, f1.y * QSC); cv.u[3] = pkbf(f1.z * QSC, f1.w * QSC);
        qfA1 = cv.s;
        const float* srcB = Qp + (size_t)(qiB * QBLK + wv * 16 + l15) * HD + dofs;
        f0 = *(const float4*)(srcB);
        f1 = *(const float4*)(srcB + 4);
        cv.u[0] = pkbf(f0.x * QSC, f0.y * QSC); cv.u[1] = pkbf(f0.z * QSC, f0.w * QSC);
        cv.u[2] = pkbf(f1.x * QSC, f1.y * QSC); cv.u[3] = pkbf(f1.z * QSC, f1.w * QSC);
        qfB0 = cv.s;
        f0 = *(const float4*)(srcB + 32);
        f1 = *(const float4*)(srcB + 36);
        cv.u[0] = pkbf(f0.x * QSC, f0.y * QSC); cv.u[1] = pkbf(f0.z * QSC, f0.w * QSC);
        cv.u[2] = pkbf(f1.x * QSC, f1.y * QSC); cv.u[3] = pkbf(f1.z * QSC, f1.w * QSC);
        qfB1 = cv.s;
    }
    short8 qf0 = qfA0, qf1 = qfA1;

    // ---- prologue: prefetch tile 0 into registers ----
    short8 krA = *(const short8*)(Kp + kg0);
    short8 krB = *(const short8*)(Kp + kg1);
    short8 vrA = *(const short8*)(Vp + vg0);
    short8 vrB = *(const short8*)(Vp + vg1);

    floatx4 o_acc[4];
    #pragma unroll
    for (int dt = 0; dt < 4; ++dt)
        #pragma unroll
        for (int e = 0; e < 4; ++e) o_acc[dt][e] = 0.0f;
    float m_s = -1e30f, l_s = 0.0f;

    for (int g = 0; g < TT; ++g) {
        const int buf = g & 1;
        *(short8*)&K_lds[buf][r0][j0 * 8]  = krA;
        *(short8*)&K_lds[buf][r1][j1 * 8]  = krB;
        *(short8*)&Vt_lds[buf][r0][j0 * 8] = vrA;
        *(short8*)&Vt_lds[buf][r1][j1 * 8] = vrB;
        __syncthreads();

        if (g + 1 < TT) {
            // next tile index: phase A runs tiles 0..qiA, then phase B 0..qiB
            const int tn = (g + 1 <= qiA) ? (g + 1) : (g - qiA);
            const short* ks = Kp + (size_t)tn * KVBLK * HD;
            const short* vs = Vp + tn * KVBLK;
            krA = *(const short8*)(ks + kg0);
            krB = *(const short8*)(ks + kg1);
            vrA = *(const short8*)(vs + vg0);
            vrB = *(const short8*)(vs + vg1);
        }

        // ---- S^T = K (Q*scale)^T : lane holds k=(lg4+r)+16n, q=l15 ----
        floatx4 s_acc[4];
        __builtin_amdgcn_s_setprio(1);
        #pragma unroll
        for (int n = 0; n < 4; ++n) {
            const short8 k0 = *(const short8*)&K_lds[buf][n * 16 + l15][dofs];
            const short8 k1 = *(const short8*)&K_lds[buf][n * 16 + l15][dofs + 32];
            floatx4 acc = {0.0f, 0.0f, 0.0f, 0.0f};
            acc = __builtin_amdgcn_mfma_f32_16x16x32_bf16(k0, qf0, acc, 0, 0, 0);
            acc = __builtin_amdgcn_mfma_f32_16x16x32_bf16(k1, qf1, acc, 0, 0, 0);
            s_acc[n] = acc;
        }
        __builtin_amdgcn_s_setprio(0);

        // ---- causal mask on each phase's diagonal tile ----
        if (g == qiA || g == TT - 1) {
            const int qlocal = wv * 16 + l15;
            #pragma unroll
            for (int n = 0; n < 4; ++n)
                #pragma unroll
                for (int r = 0; r < 4; ++r)
                    if (n * 16 + lg4 + r > qlocal) s_acc[n][r] = -1e30f;
        }

        // ---- online softmax: in-lane tree + 2 cross-group shfls ----
        float t0 = fmaxf(fmaxf(s_acc[0][0], s_acc[0][1]), fmaxf(s_acc[0][2], s_acc[0][3]));
        float t1 = fmaxf(fmaxf(s_acc[1][0], s_acc[1][1]), fmaxf(s_acc[1][2], s_acc[1][3]));
        float t2 = fmaxf(fmaxf(s_acc[2][0], s_acc[2][1]), fmaxf(s_acc[2][2], s_acc[2][3]));
        float t3 = fmaxf(fmaxf(s_acc[3][0], s_acc[3][1]), fmaxf(s_acc[3][2], s_acc[3][3]));
        float rmax = fmaxf(fmaxf(t0, t1), fmaxf(t2, t3));
        rmax = fmaxf(rmax, __shfl_xor(rmax, 16));
        rmax = fmaxf(rmax, __shfl_xor(rmax, 32));

        const bool trig = rmax > m_s + THR;
        float alpha = 1.0f;
        if (trig) {
            alpha = EXP2(m_s - rmax);
            m_s = rmax;
            l_s *= alpha;
        }
        if (__any(trig)) {
            // o_acc row e is q=lg4+e; its alpha lives in lane (lg4+e) (l15==q)
            float a0 = __shfl(alpha, lg4 + 0);
            float a1 = __shfl(alpha, lg4 + 1);
            float a2 = __shfl(alpha, lg4 + 2);
            float a3 = __shfl(alpha, lg4 + 3);
            #pragma unroll
            for (int dt = 0; dt < 4; ++dt) {
                o_acc[dt][0] *= a0; o_acc[dt][1] *= a1;
                o_acc[dt][2] *= a2; o_acc[dt][3] *= a3;
            }
        }

        float lsum;
        {
            float p00 = EXP2(s_acc[0][0] - m_s), p01 = EXP2(s_acc[0][1] - m_s);
            float p02 = EXP2(s_acc[0][2] - m_s), p03 = EXP2(s_acc[0][3] - m_s);
            float p10 = EXP2(s_acc[1][0] - m_s), p11 = EXP2(s_acc[1][1] - m_s);
            float p12 = EXP2(s_acc[1][2] - m_s), p13 = EXP2(s_acc[1][3] - m_s);
            float p20 = EXP2(s_acc[2][0] - m_s), p21 = EXP2(s_acc[2][1] - m_s);
            float p22 = EXP2(s_acc[2][2] - m_s), p23 = EXP2(s_acc[2][3] - m_s);
            float p30 = EXP2(s_acc[3][0] - m_s), p31 = EXP2(s_acc[3][1] - m_s);
            float p32 = EXP2(s_acc[3][2] - m_s), p33 = EXP2(s_acc[3][3] - m_s);
            lsum = ((p00 + p01) + (p02 + p03)) + ((p10 + p11) + (p12 + p13))
                 + ((p20 + p21) + (p22 + p23)) + ((p30 + p31) + (p32 + p33));
            uint2v w;
            short* prow = &Pl[wv][l15][lg4];
            w[0] = pkbf(p00, p01); w[1] = pkbf(p02, p03);
            *(uint2v*)(prow)      = w;
            w[0] = pkbf(p10, p11); w[1] = pkbf(p12, p13);
            *(uint2v*)(prow + 16) = w;
            w[0] = pkbf(p20, p21); w[1] = pkbf(p22, p23);
            *(uint2v*)(prow + 32) = w;
            w[0] = pkbf(p30, p31); w[1] = pkbf(p32, p33);
            *(uint2v*)(prow + 48) = w;
        }
        l_s += lsum;

        // wave-local LDS RAW: wait for this wave's ds_writes
        asm volatile("s_waitcnt lgkmcnt(0)" ::: "memory");

        // ---- O += P V ----
        const short8 p0 = *(const short8*)&Pl[wv][l15][dofs];
        const short8 p1 = *(const short8*)&Pl[wv][l15][dofs + 32];
        __builtin_amdgcn_s_setprio(1);
        #pragma unroll
        for (int dt = 0; dt < 4; ++dt) {
            const short8 v0 = *(const short8*)&Vt_lds[buf][dt * 16 + l15][dofs];
            const short8 v1 = *(const short8*)&Vt_lds[buf][dt * 16 + l15][dofs + 32];
            o_acc[dt] = __builtin_amdgcn_mfma_f32_16x16x32_bf16(p0, v0, o_acc[dt], 0, 0, 0);
            o_acc[dt] = __builtin_amdgcn_mfma_f32_16x16x32_bf16(p1, v1, o_acc[dt], 0, 0, 0);
        }
        __builtin_amdgcn_s_setprio(0);

        // ---- phase A -> B transition: store A, reset state ----
        if (g == qiA) {
            FINAL_STORE(qiA * QBLK);
            #pragma unroll
            for (int dt = 0; dt < 4; ++dt)
                #pragma unroll
                for (int e = 0; e < 4; ++e) o_acc[dt][e] = 0.0f;
            m_s = -1e30f; l_s = 0.0f;
            qf0 = qfB0; qf1 = qfB1;
        }
    }

    FINAL_STORE(qiB * QBLK);
}

// ---------------- fallback (round-1 kernel, proven) if ws too small ----------------

__global__ __launch_bounds__(256, 2)
void fa_fwd_v1(const float* __restrict__ Q, const float* __restrict__ K,
               const float* __restrict__ V, float* __restrict__ O)
{
    const int tid  = threadIdx.x;
    const int lane = tid & 63;
    const int wv   = tid >> 6;
    const int l15  = lane & 15;
    const int lg   = lane >> 4;
    const int dofs = lg * 8;
    const int bh = blockIdx.x & (NBH - 1);
    const int qi = 31 - (blockIdx.x >> 5);
    const size_t base = (size_t)bh * SEQ * HD;
    const float* Qp = Q + base; const float* Kp = K + base;
    const float* Vp = V + base; float* Op = O + base;
    const int qbase = qi * 64;
    __shared__ __align__(16) short K_lds[64][72];
    __shared__ __align__(16) short Vt_lds[HD][72];
    __shared__ __align__(16) short P_lds[4][16][72];
    short8 qfrag[2];
    {
        const float* src = Qp + (size_t)(qbase + wv * 16 + l15) * HD + dofs;
        #pragma unroll
        for (int c = 0; c < 2; ++c) {
            float4 f0 = *(const float4*)(src + 32 * c);
            float4 f1 = *(const float4*)(src + 32 * c + 4);
            short8 tt;
            tt[0] = f2bf(f0.x * 0.125f); tt[1] = f2bf(f0.y * 0.125f);
            tt[2] = f2bf(f0.z * 0.125f); tt[3] = f2bf(f0.w * 0.125f);
            tt[4] = f2bf(f1.x * 0.125f); tt[5] = f2bf(f1.y * 0.125f);
            tt[6] = f2bf(f1.z * 0.125f); tt[7] = f2bf(f1.w * 0.125f);
            qfrag[c] = tt;
        }
    }
    floatx4 o_acc[4];
    #pragma unroll
    for (int dt = 0; dt < 4; ++dt)
        #pragma unroll
        for (int e = 0; e < 4; ++e) o_acc[dt][e] = 0.0f;
    float m_r[4], l_r[4];
    #pragma unroll
    for (int r = 0; r < 4; ++r) { m_r[r] = -1e30f; l_r[r] = 0.0f; }
    for (int t = 0; t <= qi; ++t) {
        __syncthreads();
        {
            const float4* ks = (const float4*)(Kp + (size_t)t * 64 * HD);
            const float4* vs = (const float4*)(Vp + (size_t)t * 64 * HD);
            #pragma unroll
            for (int j = 0; j < 4; ++j) {
                int idx = j * 256 + tid;
                int row = idx >> 4;
                int col = (idx & 15) << 2;
                float4 kf = ks[idx];
                K_lds[row][col + 0] = f2bf(kf.x); K_lds[row][col + 1] = f2bf(kf.y);
                K_lds[row][col + 2] = f2bf(kf.z); K_lds[row][col + 3] = f2bf(kf.w);
                float4 vf = vs[idx];
                Vt_lds[col + 0][row] = f2bf(vf.x); Vt_lds[col + 1][row] = f2bf(vf.y);
                Vt_lds[col + 2][row] = f2bf(vf.z); Vt_lds[col + 3][row] = f2bf(vf.w);
            }
        }
        __syncthreads();
        floatx4 s_acc[4];
        #pragma unroll
        for (int n = 0; n < 4; ++n) {
            const short8 k0 = *(const short8*)&K_lds[n * 16 + l15][dofs];
            const short8 k1 = *(const short8*)&K_lds[n * 16 + l15][dofs + 32];
            floatx4 acc = {0.0f, 0.0f, 0.0f, 0.0f};
            acc = __builtin_amdgcn_mfma_f32_16x16x32_bf16(qfrag[0], k0, acc, 0, 0, 0);
            acc = __builtin_amdgcn_mfma_f32_16x16x32_bf16(qfrag[1], k1, acc, 0, 0, 0);
            s_acc[n] = acc;
        }
        if (t == qi) {
            #pragma unroll
            for (int n = 0; n < 4; ++n)
                #pragma unroll
                for (int r = 0; r < 4; ++r) {
                    int qr = wv * 16 + lg * 4 + r;
                    int kc = n * 16 + l15;
                    if (kc > qr) s_acc[n][r] = -1e30f;
                }
        }
        #pragma unroll
        for (int r = 0; r < 4; ++r) {
            float rmax = fmaxf(fmaxf(s_acc[0][r], s_acc[1][r]),
                               fmaxf(s_acc[2][r], s_acc[3][r]));
            rmax = fmaxf(rmax, __shfl_xor(rmax, 1));
            rmax = fmaxf(rmax, __shfl_xor(rmax, 2));
            rmax = fmaxf(rmax, __shfl_xor(rmax, 4));
            rmax = fmaxf(rmax, __shfl_xor(rmax, 8));
            float mnew  = fmaxf(m_r[r], rmax);
            float alpha = __expf(m_r[r] - mnew);
            m_r[r] = mnew;
            l_r[r] *= alpha;
            #pragma unroll
            for (int dt = 0; dt < 4; ++dt) o_acc[dt][r] *= alpha;
            #pragma unroll
            for (int n = 0; n < 4; ++n) {
                float p = __expf(s_acc[n][r] - mnew);
                l_r[r] += p;
                P_lds[wv][lg * 4 + r][n * 16 + l15] = f2bf(p);
            }
        }
        asm volatile("s_waitcnt lgkmcnt(0)" ::: "memory");
        const short8 p0 = *(const short8*)&P_lds[wv][l15][dofs];
        const short8 p1 = *(const short8*)&P_lds[wv][l15][dofs + 32];
        #pragma unroll
        for (int dt = 0; dt < 4; ++dt) {
            const short8 v0 = *(const short8*)&Vt_lds[dt * 16 + l15][dofs];
            const short8 v1 = *(const short8*)&Vt_lds[dt * 16 + l15][dofs + 32];
            o_acc[dt] = __builtin_amdgcn_mfma_f32_16x16x32_bf16(p0, v0, o_acc[dt], 0, 0, 0);
            o_acc[dt] = __builtin_amdgcn_mfma_f32_16x16x32_bf16(p1, v1, o_acc[dt], 0, 0, 0);
        }
    }
    #pragma unroll
    for (int r = 0; r < 4; ++r) {
        float l = l_r[r];
        l += __shfl_xor(l, 1);
        l += __shfl_xor(l, 2);
        l += __shfl_xor(l, 4);
        l += __shfl_xor(l, 8);
        l_r[r] = 1.0f / l;
    }
    #pragma unroll
    for (int dt = 0; dt < 4; ++dt)
        #pragma unroll
        for (int r = 0; r < 4; ++r) {
            int row = qbase + wv * 16 + lg * 4 + r;
            Op[(size_t)row * HD + dt * 16 + l15] = o_acc[dt][r] * l_r[r];
        }
}

extern "C" void kernel_launch(void* const* d_in, const int* in_sizes, int n_in,
                              void* d_out, int out_size, void* d_ws, size_t ws_size,
                              hipStream_t stream) {
    const float* q = (const float*)d_in[0];
    const float* k = (const float*)d_in[1];
    const float* v = (const float*)d_in[2];
    float* o = (float*)d_out;
    (void)in_sizes; (void)n_in; (void)out_size;

    const size_t elems = (size_t)NBH * SEQ * HD;
    const size_t need  = 2 * elems * sizeof(short);
    if (ws_size >= need) {
        short* kb = (short*)d_ws;
        short* vt = kb + elems;
        conv_k_kernel<<<dim3(elems / (256 * 8)), dim3(256), 0, stream>>>(k, kb);
        trans_v_kernel<<<dim3(NBH * 32), dim3(256), 0, stream>>>(v, vt);
        fa_fwd_v8<<<dim3(NBH * (NQT / 2)), dim3(256), 0, stream>>>(q, kb, vt, o);
    } else {
        fa_fwd_v1<<<dim3(NBH * 32), dim3(256), 0, stream>>>(q, k, v, o);
    }
}

// Round 9
// 53.775 us; speedup vs baseline: 1.1440x; 1.1440x over previous
//
#include <hip/hip_runtime.h>
#include <hip/hip_bf16.h>
#include <cstdint>

#define SEQ   2048
#define HD    64
#define NBH   32
#define QBLK  64
#define KVBLK 64
#define NQT   (SEQ / QBLK)  // 32
#define LDK   72            // padded LDS stride (shorts): 144B rows
// scale = 1/sqrt(64) * log2(e)  (softmax in exp2 domain)
#define QSC   0.18033688011112042f
#define THR   11.0f         // defer-max threshold (log2 domain)

typedef __attribute__((ext_vector_type(8))) short short8;
typedef __attribute__((ext_vector_type(4))) float floatx4;

#if __has_builtin(__builtin_amdgcn_exp2f)
#define EXP2(x) __builtin_amdgcn_exp2f(x)
#else
#define EXP2(x) __expf((x) * 0.69314718055994531f)
#endif

static __device__ __forceinline__ short f2bf(float f) {
    union { float f; unsigned u; } x; x.f = f;
    return (short)((x.u + 0x7fffu + ((x.u >> 16) & 1u)) >> 16);  // RNE
}
static __device__ __forceinline__ unsigned pkbf(float a, float b) {
    __hip_bfloat162 h = __float22bfloat162_rn(make_float2(a, b));
    union { __hip_bfloat162 h; unsigned u; } c; c.h = h; return c.u;
}

// ---------------- prep kernels (proven) ----------------

__global__ __launch_bounds__(256)
void conv_k_kernel(const float* __restrict__ K, short* __restrict__ Kb) {
    size_t i = ((size_t)blockIdx.x * 256 + threadIdx.x) * 8;
    float4 a = *(const float4*)(K + i);
    float4 b = *(const float4*)(K + i + 4);
    union { unsigned u[4]; short8 s; } cv;
    cv.u[0] = pkbf(a.x, a.y); cv.u[1] = pkbf(a.z, a.w);
    cv.u[2] = pkbf(b.x, b.y); cv.u[3] = pkbf(b.z, b.w);
    *(short8*)(Kb + i) = cv.s;
}

__global__ __launch_bounds__(256)
void trans_v_kernel(const float* __restrict__ V, short* __restrict__ Vt) {
    __shared__ __align__(16) short Vs[64][72];
    const int tid = threadIdx.x;
    const int bh = blockIdx.x >> 5;
    const int t  = blockIdx.x & 31;
    const float* src = V + ((size_t)bh * SEQ + (size_t)t * 64) * HD;
    #pragma unroll
    for (int i = 0; i < 4; ++i) {
        int idx = i * 256 + tid;
        int r = idx >> 4; int c = (idx & 15) * 4;
        float4 f = *(const float4*)(src + r * HD + c);
        Vs[c + 0][r] = f2bf(f.x); Vs[c + 1][r] = f2bf(f.y);
        Vs[c + 2][r] = f2bf(f.z); Vs[c + 3][r] = f2bf(f.w);
    }
    __syncthreads();
    short* dst = Vt + (size_t)bh * HD * SEQ + t * 64;
    #pragma unroll
    for (int i = 0; i < 2; ++i) {
        int idx = i * 256 + tid;
        int d = idx >> 3; int j = idx & 7;
        short8 v = *(const short8*)&Vs[d][j * 8];
        *(short8*)(dst + (size_t)d * SEQ + j * 8) = v;
    }
}

// ---------------- main attention kernel (v9) ----------------
// v7b structure (1024 heavy-first blocks, 4 waves x 16 q, dbuf K/V with one
// barrier/tile, reg-prefetch, swapped QK^T, lane-local softmax, defer-max,
// setprio) + ZERO-LDS P: K-row permutation {0,4,32,36} makes each lane's
// QK^T outputs land exactly in the PV A-fragment layout (k = 8*lg + e),
// so P is packed in-register (8 pkbf) and fed straight to PV. No Pl buffer,
// no ds_write/lgkmcnt/ds_read on the critical path. LDS 46->36.9 KB.

__global__ __launch_bounds__(256, 4)
void fa_fwd_v9(const float* __restrict__ Q, const short* __restrict__ Kg,
               const short* __restrict__ Vtg, float* __restrict__ O)
{
    const int tid  = threadIdx.x;
    const int lane = tid & 63;
    const int wv   = tid >> 6;
    const int l15  = lane & 15;
    const int lg   = lane >> 4;
    const int lg4  = lg * 4;
    const int dofs = lg * 8;

    const int bh = blockIdx.x & (NBH - 1);
    const int qi = (NQT - 1) - (blockIdx.x >> 5);   // heavy tiles first
    const int qbase = qi * QBLK;

    const float* Qp = Q   + (size_t)bh * SEQ * HD;
    const short* Kp = Kg  + (size_t)bh * SEQ * HD;
    const short* Vp = Vtg + (size_t)bh * HD * SEQ;
    float*       Op = O   + (size_t)bh * SEQ * HD;

    __shared__ __align__(16) short K_lds[2][KVBLK][LDK];
    __shared__ __align__(16) short Vt_lds[2][HD][LDK];

    const int r0 = tid >> 3,         j0 = tid & 7;
    const int r1 = (tid + 256) >> 3, j1 = tid & 7;
    const int kg0 = r0 * HD + j0 * 8, kg1 = r1 * HD + j1 * 8;
    const int vg0 = r0 * SEQ + j0 * 8, vg1 = r1 * SEQ + j1 * 8;

    // permuted K-row base: call n reads row rowb + {0,4,32,36}[n]
    const int rowb = ((l15 & ~3) << 1) + (l15 & 3);   // 8*(l15>>2) + (l15&3)
    const int kb   = 8 * lg;                           // lane's k base

    // ---- Q fragments (B-operand), scale folded ----
    short8 qf0, qf1;
    {
        const float* src = Qp + (size_t)(qbase + wv * 16 + l15) * HD + dofs;
        union { unsigned u[4]; short8 s; } cv;
        float4 f0 = *(const float4*)(src);
        float4 f1 = *(const float4*)(src + 4);
        cv.u[0] = pkbf(f0.x * QSC, f0.y * QSC); cv.u[1] = pkbf(f0.z * QSC, f0.w * QSC);
        cv.u[2] = pkbf(f1.x * QSC, f1.y * QSC); cv.u[3] = pkbf(f1.z * QSC, f1.w * QSC);
        qf0 = cv.s;
        f0 = *(const float4*)(src + 32);
        f1 = *(const float4*)(src + 36);
        cv.u[0] = pkbf(f0.x * QSC, f0.y * QSC); cv.u[1] = pkbf(f0.z * QSC, f0.w * QSC);
        cv.u[2] = pkbf(f1.x * QSC, f1.y * QSC); cv.u[3] = pkbf(f1.z * QSC, f1.w * QSC);
        qf1 = cv.s;
    }

    // ---- prologue: prefetch tile 0 into registers ----
    short8 krA = *(const short8*)(Kp + kg0);
    short8 krB = *(const short8*)(Kp + kg1);
    short8 vrA = *(const short8*)(Vp + vg0);
    short8 vrB = *(const short8*)(Vp + vg1);

    floatx4 o_acc[4];
    #pragma unroll
    for (int dt = 0; dt < 4; ++dt)
        #pragma unroll
        for (int e = 0; e < 4; ++e) o_acc[dt][e] = 0.0f;
    float m_s = -1e30f, l_s = 0.0f;

    for (int t = 0; t <= qi; ++t) {
        const int buf = t & 1;
        *(short8*)&K_lds[buf][r0][j0 * 8]  = krA;
        *(short8*)&K_lds[buf][r1][j1 * 8]  = krB;
        *(short8*)&Vt_lds[buf][r0][j0 * 8] = vrA;
        *(short8*)&Vt_lds[buf][r1][j1 * 8] = vrB;
        __syncthreads();

        if (t < qi) {
            const short* ks = Kp + (size_t)(t + 1) * KVBLK * HD;
            const short* vs = Vp + (t + 1) * KVBLK;
            krA = *(const short8*)(ks + kg0);
            krB = *(const short8*)(ks + kg1);
            vrA = *(const short8*)(vs + vg0);
            vrB = *(const short8*)(vs + vg1);
        }

        // ---- S^T = K (Q*scale)^T with permuted rows:
        //      s_acc[n][r] = S[k = kb + roff[n] + r][q = l15] ----
        const int roff[4] = {0, 4, 32, 36};
        floatx4 s_acc[4];
        __builtin_amdgcn_s_setprio(1);
        #pragma unroll
        for (int n = 0; n < 4; ++n) {
            const short* krow = &K_lds[buf][rowb + roff[n]][0];
            const short8 k0 = *(const short8*)(krow + dofs);
            const short8 k1 = *(const short8*)(krow + dofs + 32);
            floatx4 acc = {0.0f, 0.0f, 0.0f, 0.0f};
            acc = __builtin_amdgcn_mfma_f32_16x16x32_bf16(k0, qf0, acc, 0, 0, 0);
            acc = __builtin_amdgcn_mfma_f32_16x16x32_bf16(k1, qf1, acc, 0, 0, 0);
            s_acc[n] = acc;
        }
        __builtin_amdgcn_s_setprio(0);

        // ---- causal mask (diagonal tile only): k_local > q_local ----
        if (t == qi) {
            const int qlocal = wv * 16 + l15;
            #pragma unroll
            for (int n = 0; n < 4; ++n)
                #pragma unroll
                for (int r = 0; r < 4; ++r)
                    if (kb + roff[n] + r > qlocal) s_acc[n][r] = -1e30f;
        }

        // ---- online softmax: in-lane tree + 2 cross-group shfls ----
        float t0 = fmaxf(fmaxf(s_acc[0][0], s_acc[0][1]), fmaxf(s_acc[0][2], s_acc[0][3]));
        float t1 = fmaxf(fmaxf(s_acc[1][0], s_acc[1][1]), fmaxf(s_acc[1][2], s_acc[1][3]));
        float t2 = fmaxf(fmaxf(s_acc[2][0], s_acc[2][1]), fmaxf(s_acc[2][2], s_acc[2][3]));
        float t3 = fmaxf(fmaxf(s_acc[3][0], s_acc[3][1]), fmaxf(s_acc[3][2], s_acc[3][3]));
        float rmax = fmaxf(fmaxf(t0, t1), fmaxf(t2, t3));
        rmax = fmaxf(rmax, __shfl_xor(rmax, 16));
        rmax = fmaxf(rmax, __shfl_xor(rmax, 32));

        const bool trig = rmax > m_s + THR;
        float alpha = 1.0f;
        if (trig) {
            alpha = EXP2(m_s - rmax);
            m_s = rmax;
            l_s *= alpha;
        }
        if (__any(trig)) {
            // o_acc row e is q=lg4+e; alpha for q lives in lane l15==q (lg=0 set)
            float a0 = __shfl(alpha, lg4 + 0);
            float a1 = __shfl(alpha, lg4 + 1);
            float a2 = __shfl(alpha, lg4 + 2);
            float a3 = __shfl(alpha, lg4 + 3);
            #pragma unroll
            for (int dt = 0; dt < 4; ++dt) {
                o_acc[dt][0] *= a0; o_acc[dt][1] *= a1;
                o_acc[dt][2] *= a2; o_acc[dt][3] *= a3;
            }
        }

        // ---- P = exp2(S - m) packed IN-REGISTER into PV A-fragments ----
        short8 p0, p1;
        {
            float p00 = EXP2(s_acc[0][0] - m_s), p01 = EXP2(s_acc[0][1] - m_s);
            float p02 = EXP2(s_acc[0][2] - m_s), p03 = EXP2(s_acc[0][3] - m_s);
            float p10 = EXP2(s_acc[1][0] - m_s), p11 = EXP2(s_acc[1][1] - m_s);
            float p12 = EXP2(s_acc[1][2] - m_s), p13 = EXP2(s_acc[1][3] - m_s);
            float p20 = EXP2(s_acc[2][0] - m_s), p21 = EXP2(s_acc[2][1] - m_s);
            float p22 = EXP2(s_acc[2][2] - m_s), p23 = EXP2(s_acc[2][3] - m_s);
            float p30 = EXP2(s_acc[3][0] - m_s), p31 = EXP2(s_acc[3][1] - m_s);
            float p32 = EXP2(s_acc[3][2] - m_s), p33 = EXP2(s_acc[3][3] - m_s);
            l_s += ((p00 + p01) + (p02 + p03)) + ((p10 + p11) + (p12 + p13))
                 + ((p20 + p21) + (p22 + p23)) + ((p30 + p31) + (p32 + p33));
            union { unsigned u[4]; short8 s; } c0, c1;
            c0.u[0] = pkbf(p00, p01); c0.u[1] = pkbf(p02, p03);   // k = kb+0..3
            c0.u[2] = pkbf(p10, p11); c0.u[3] = pkbf(p12, p13);   // k = kb+4..7
            c1.u[0] = pkbf(p20, p21); c1.u[1] = pkbf(p22, p23);   // k = 32+kb+0..3
            c1.u[2] = pkbf(p30, p31); c1.u[3] = pkbf(p32, p33);   // k = 32+kb+4..7
            p0 = c0.s; p1 = c1.s;
        }

        // ---- O += P V (P already in A-fragment layout) ----
        __builtin_amdgcn_s_setprio(1);
        #pragma unroll
        for (int dt = 0; dt < 4; ++dt) {
            const short8 v0 = *(const short8*)&Vt_lds[buf][dt * 16 + l15][dofs];
            const short8 v1 = *(const short8*)&Vt_lds[buf][dt * 16 + l15][dofs + 32];
            o_acc[dt] = __builtin_amdgcn_mfma_f32_16x16x32_bf16(p0, v0, o_acc[dt], 0, 0, 0);
            o_acc[dt] = __builtin_amdgcn_mfma_f32_16x16x32_bf16(p1, v1, o_acc[dt], 0, 0, 0);
        }
        __builtin_amdgcn_s_setprio(0);
    }

    // ---- finalize ----
    l_s += __shfl_xor(l_s, 16);
    l_s += __shfl_xor(l_s, 32);
    const float linv = 1.0f / l_s;
    #pragma unroll
    for (int e = 0; e < 4; ++e) {
        const float li = __shfl(linv, lg4 + e);
        const int row = qbase + wv * 16 + lg4 + e;
        #pragma unroll
        for (int dt = 0; dt < 4; ++dt)
            Op[(size_t)row * HD + dt * 16 + l15] = o_acc[dt][e] * li;
    }
}

// ---------------- fallback (round-1 kernel, proven) if ws too small ----------------

__global__ __launch_bounds__(256, 2)
void fa_fwd_v1(const float* __restrict__ Q, const float* __restrict__ K,
               const float* __restrict__ V, float* __restrict__ O)
{
    const int tid  = threadIdx.x;
    const int lane = tid & 63;
    const int wv   = tid >> 6;
    const int l15  = lane & 15;
    const int lg   = lane >> 4;
    const int dofs = lg * 8;
    const int bh = blockIdx.x & (NBH - 1);
    const int qi = 31 - (blockIdx.x >> 5);
    const size_t base = (size_t)bh * SEQ * HD;
    const float* Qp = Q + base; const float* Kp = K + base;
    const float* Vp = V + base; float* Op = O + base;
    const int qbase = qi * 64;
    __shared__ __align__(16) short K_lds[64][72];
    __shared__ __align__(16) short Vt_lds[HD][72];
    __shared__ __align__(16) short P_lds[4][16][72];
    short8 qfrag[2];
    {
        const float* src = Qp + (size_t)(qbase + wv * 16 + l15) * HD + dofs;
        #pragma unroll
        for (int c = 0; c < 2; ++c) {
            float4 f0 = *(const float4*)(src + 32 * c);
            float4 f1 = *(const float4*)(src + 32 * c + 4);
            short8 tt;
            tt[0] = f2bf(f0.x * 0.125f); tt[1] = f2bf(f0.y * 0.125f);
            tt[2] = f2bf(f0.z * 0.125f); tt[3] = f2bf(f0.w * 0.125f);
            tt[4] = f2bf(f1.x * 0.125f); tt[5] = f2bf(f1.y * 0.125f);
            tt[6] = f2bf(f1.z * 0.125f); tt[7] = f2bf(f1.w * 0.125f);
            qfrag[c] = tt;
        }
    }
    floatx4 o_acc[4];
    #pragma unroll
    for (int dt = 0; dt < 4; ++dt)
        #pragma unroll
        for (int e = 0; e < 4; ++e) o_acc[dt][e] = 0.0f;
    float m_r[4], l_r[4];
    #pragma unroll
    for (int r = 0; r < 4; ++r) { m_r[r] = -1e30f; l_r[r] = 0.0f; }
    for (int t = 0; t <= qi; ++t) {
        __syncthreads();
        {
            const float4* ks = (const float4*)(Kp + (size_t)t * 64 * HD);
            const float4* vs = (const float4*)(Vp + (size_t)t * 64 * HD);
            #pragma unroll
            for (int j = 0; j < 4; ++j) {
                int idx = j * 256 + tid;
                int row = idx >> 4;
                int col = (idx & 15) << 2;
                float4 kf = ks[idx];
                K_lds[row][col + 0] = f2bf(kf.x); K_lds[row][col + 1] = f2bf(kf.y);
                K_lds[row][col + 2] = f2bf(kf.z); K_lds[row][col + 3] = f2bf(kf.w);
                float4 vf = vs[idx];
                Vt_lds[col + 0][row] = f2bf(vf.x); Vt_lds[col + 1][row] = f2bf(vf.y);
                Vt_lds[col + 2][row] = f2bf(vf.z); Vt_lds[col + 3][row] = f2bf(vf.w);
            }
        }
        __syncthreads();
        floatx4 s_acc[4];
        #pragma unroll
        for (int n = 0; n < 4; ++n) {
            const short8 k0 = *(const short8*)&K_lds[n * 16 + l15][dofs];
            const short8 k1 = *(const short8*)&K_lds[n * 16 + l15][dofs + 32];
            floatx4 acc = {0.0f, 0.0f, 0.0f, 0.0f};
            acc = __builtin_amdgcn_mfma_f32_16x16x32_bf16(qfrag[0], k0, acc, 0, 0, 0);
            acc = __builtin_amdgcn_mfma_f32_16x16x32_bf16(qfrag[1], k1, acc, 0, 0, 0);
            s_acc[n] = acc;
        }
        if (t == qi) {
            #pragma unroll
            for (int n = 0; n < 4; ++n)
                #pragma unroll
                for (int r = 0; r < 4; ++r) {
                    int qr = wv * 16 + lg * 4 + r;
                    int kc = n * 16 + l15;
                    if (kc > qr) s_acc[n][r] = -1e30f;
                }
        }
        #pragma unroll
        for (int r = 0; r < 4; ++r) {
            float rmax = fmaxf(fmaxf(s_acc[0][r], s_acc[1][r]),
                               fmaxf(s_acc[2][r], s_acc[3][r]));
            rmax = fmaxf(rmax, __shfl_xor(rmax, 1));
            rmax = fmaxf(rmax, __shfl_xor(rmax, 2));
            rmax = fmaxf(rmax, __shfl_xor(rmax, 4));
            rmax = fmaxf(rmax, __shfl_xor(rmax, 8));
            float mnew  = fmaxf(m_r[r], rmax);
            float alpha = __expf(m_r[r] - mnew);
            m_r[r] = mnew;
            l_r[r] *= alpha;
            #pragma unroll
            for (int dt = 0; dt < 4; ++dt) o_acc[dt][r] *= alpha;
            #pragma unroll
            for (int n = 0; n < 4; ++n) {
                float p = __expf(s_acc[n][r] - mnew);
                l_r[r] += p;
                P_lds[wv][lg * 4 + r][n * 16 + l15] = f2bf(p);
            }
        }
        asm volatile("s_waitcnt lgkmcnt(0)" ::: "memory");
        const short8 p0 = *(const short8*)&P_lds[wv][l15][dofs];
        const short8 p1 = *(const short8*)&P_lds[wv][l15][dofs + 32];
        #pragma unroll
        for (int dt = 0; dt < 4; ++dt) {
            const short8 v0 = *(const short8*)&Vt_lds[dt * 16 + l15][dofs];
            const short8 v1 = *(const short8*)&Vt_lds[dt * 16 + l15][dofs + 32];
            o_acc[dt] = __builtin_amdgcn_mfma_f32_16x16x32_bf16(p0, v0, o_acc[dt], 0, 0, 0);
            o_acc[dt] = __builtin_amdgcn_mfma_f32_16x16x32_bf16(p1, v1, o_acc[dt], 0, 0, 0);
        }
    }
    #pragma unroll
    for (int r = 0; r < 4; ++r) {
        float l = l_r[r];
        l += __shfl_xor(l, 1);
        l += __shfl_xor(l, 2);
        l += __shfl_xor(l, 4);
        l += __shfl_xor(l, 8);
        l_r[r] = 1.0f / l;
    }
    #pragma unroll
    for (int dt = 0; dt < 4; ++dt)
        #pragma unroll
        for (int r = 0; r < 4; ++r) {
            int row = qbase + wv * 16 + lg * 4 + r;
            Op[(size_t)row * HD + dt * 16 + l15] = o_acc[dt][r] * l_r[r];
        }
}

extern "C" void kernel_launch(void* const* d_in, const int* in_sizes, int n_in,
                              void* d_out, int out_size, void* d_ws, size_t ws_size,
                              hipStream_t stream) {
    const float* q = (const float*)d_in[0];
    const float* k = (const float*)d_in[1];
    const float* v = (const float*)d_in[2];
    float* o = (float*)d_out;
    (void)in_sizes; (void)n_in; (void)out_size;

    const size_t elems = (size_t)NBH * SEQ * HD;
    const size_t need  = 2 * elems * sizeof(short);
    if (ws_size >= need) {
        short* kb = (short*)d_ws;
        short* vt = kb + elems;
        conv_k_kernel<<<dim3(elems / (256 * 8)), dim3(256), 0, stream>>>(k, kb);
        trans_v_kernel<<<dim3(NBH * 32), dim3(256), 0, stream>>>(v, vt);
        fa_fwd_v9<<<dim3(NBH * NQT), dim3(256), 0, stream>>>(q, kb, vt, o);
    } else {
        fa_fwd_v1<<<dim3(NBH * 32), dim3(256), 0, stream>>>(q, k, v, o);
    }
}